// Round 1
// 364.214 us; speedup vs baseline: 1.0851x; 1.0851x over previous
//
#include <hip/hip_runtime.h>
#include <hip/hip_bf16.h>

// ---------------------------------------------------------------------------
// GCN forward: hierarchical atomic-free CSR build (256-node buckets,
// 8-padded per-node lists) -> 3x (MFMA-bf16 GEMM w/ fused dis-scale + bf16
// store -> padded colidx gather aggregate) -> fused pool+FC head.
// hs = dis[n]*h[n] in bf16 (+zero dummy row N). Inter-layer bufs bf16.
// k_agg lane map: eslot(0..7) x ch-octet(0..7); 16B uint4 gathers -> 8 edges
// per VMEM instruction; butterfly over eslot.
// NOTE (R5): NO float LDS atomics — CAS loop, ~20x cost.
// NOTE (R8): do NOT fuse gather into GEMM tile — needs one-wave-per-node TLP.
// NOTE (R9): NBLK=1024 regressed build (short scatter runs + 4x blockhist);
// 256 partition blocks + 256-node buckets maximize scatter run length.
// NOTE (R10): k_agg accumulate is the top VALU consumer (VALUBusy 50% was
// ~all unpack+add). v_pk_add_f32 pairs + colidx stores src<<7 byte offsets
// + pad-to-8 (not 16). k_head2 widened to 4 waves/block (was 512 serial
// waves chip-wide, latency-bound).
// ---------------------------------------------------------------------------

#define NBLK 256        // partition blocks
#define MAXNB 512       // max buckets (N <= 131072 at 256 nodes/bucket)
#define FCAP 9216       // LDS edge-staging capacity in k_fine (36 KB)
#define BPAD 2048       // per-bucket colidx padding slack (256 * 7 max)

typedef __attribute__((ext_vector_type(8))) short short8;    // 8 bf16 (4 VGPR)
typedef __attribute__((ext_vector_type(4))) float floatx4;   // MFMA acc
typedef __attribute__((ext_vector_type(2))) float f32x2;     // v_pk_add_f32 pair

__device__ __forceinline__ float bf2f(unsigned short v) {
    return __uint_as_float(((unsigned int)v) << 16);
}
__device__ __forceinline__ unsigned short f2bf(float x) {
    __hip_bfloat16 b = __float2bfloat16(x);  // round-to-nearest
    return *(unsigned short*)&b;
}
// packed accumulate: a(pair of f32) += (bf16lo, bf16hi) of u — 3 VALU ops vs 4
__device__ __forceinline__ void pkacc(f32x2& a, unsigned int u) {
    f32x2 p;
    p.x = __uint_as_float(u << 16);
    p.y = __uint_as_float(u & 0xFFFF0000u);
    asm("v_pk_add_f32 %0, %1, %0" : "+v"(a) : "v"(p));
}
// accumulate 8 bf16 (packed uint4) into 4 f32-pairs
__device__ __forceinline__ void accp(f32x2* a, uint4 u) {
    pkacc(a[0], u.x);
    pkacc(a[1], u.y);
    pkacc(a[2], u.z);
    pkacc(a[3], u.w);
}

// P1: per-block bucket histogram (int4-vectorized edge reads). bucket = dst>>8.
__global__ __launch_bounds__(256) void k_hist(const int* __restrict__ dst,
                                              int* __restrict__ blockhist,
                                              int E, int chunk, int nb) {
    __shared__ int h[MAXNB];
    int b = blockIdx.x, t = threadIdx.x;
    for (int j = t; j < nb; j += 256) h[j] = 0;
    __syncthreads();
    int lo = b * chunk, hi = min(lo + chunk, E);
    int m = hi - lo;
    if (m < 0) m = 0;
    int nv = m >> 2;
    const int4* d4 = (const int4*)(dst + lo);
    for (int i = t; i < nv; i += 256) {
        int4 v = d4[i];
        atomicAdd(&h[v.x >> 8], 1);
        atomicAdd(&h[v.y >> 8], 1);
        atomicAdd(&h[v.z >> 8], 1);
        atomicAdd(&h[v.w >> 8], 1);
    }
    for (int i = lo + (nv << 2) + t; i < hi; i += 256) atomicAdd(&h[dst[i] >> 8], 1);
    __syncthreads();
    for (int j = t; j < nb; j += 256) blockhist[j * NBLK + b] = h[j];
}

// P2a: per-bucket exclusive scan over NBLK=256 blocks (in place); btotal[j].
__global__ __launch_bounds__(256) void k_bscan(int* __restrict__ blockhist,
                                               int* __restrict__ btotal) {
    __shared__ int sm[256];
    int j = blockIdx.x, t = threadIdx.x;
    int v = blockhist[j * NBLK + t];
    sm[t] = v;
    __syncthreads();
    for (int d = 1; d < 256; d <<= 1) {
        int u = (t >= d) ? sm[t - d] : 0;
        __syncthreads();
        sm[t] += u;
        __syncthreads();
    }
    blockhist[j * NBLK + t] = sm[t] - v;
    if (t == 255) btotal[j] = sm[255];
}

// P2b: single-block exclusive scan of bucket totals -> starts[0..nb].
// Also zeroes the dummy hs rows (index N) of both ping-pong buffers.
__global__ __launch_bounds__(256) void k_sscan(const int* __restrict__ btotal,
                                               int* __restrict__ starts, int nb,
                                               unsigned short* __restrict__ z1,
                                               unsigned short* __restrict__ z2,
                                               int N) {
    __shared__ int sm[256];
    int t = threadIdx.x;
    if (t < 64) {
        z1[(size_t)N * 64 + t] = 0;
        z2[(size_t)N * 64 + t] = 0;
    }
    int base = t * 2;
    int v0 = (base + 0 < nb) ? btotal[base + 0] : 0;
    int v1 = (base + 1 < nb) ? btotal[base + 1] : 0;
    int tsum = v0 + v1;
    sm[t] = tsum;
    __syncthreads();
    for (int d = 1; d < 256; d <<= 1) {
        int u = (t >= d) ? sm[t - d] : 0;
        __syncthreads();
        sm[t] += u;
        __syncthreads();
    }
    int excl = sm[t] - tsum;
    if (base + 0 < nb) starts[base + 0] = excl;
    if (base + 1 < nb) starts[base + 1] = excl + v0;
    if (t == 255) starts[nb] = sm[255];
}

// P3: partition edges into bucket regions. epart = src | (dst&255)<<17.
__global__ __launch_bounds__(256) void k_part(const int* __restrict__ src,
                                              const int* __restrict__ dst,
                                              const int* __restrict__ blockhist,
                                              const int* __restrict__ starts,
                                              unsigned int* __restrict__ epart,
                                              int E, int chunk, int nb) {
    __shared__ int cur[MAXNB];
    int b = blockIdx.x, t = threadIdx.x;
    for (int j = t; j < nb; j += 256) cur[j] = starts[j] + blockhist[j * NBLK + b];
    __syncthreads();
    int lo = b * chunk, hi = min(lo + chunk, E);
    int m = hi - lo;
    if (m < 0) m = 0;
    int nv = m >> 2;
    const int4* d4 = (const int4*)(dst + lo);
    const int4* s4 = (const int4*)(src + lo);
    for (int i = t; i < nv; i += 256) {
        int4 d = d4[i];
        int4 s = s4[i];
        int p;
        p = atomicAdd(&cur[d.x >> 8], 1); epart[p] = (unsigned int)s.x | ((unsigned int)(d.x & 255) << 17);
        p = atomicAdd(&cur[d.y >> 8], 1); epart[p] = (unsigned int)s.y | ((unsigned int)(d.y & 255) << 17);
        p = atomicAdd(&cur[d.z >> 8], 1); epart[p] = (unsigned int)s.z | ((unsigned int)(d.z & 255) << 17);
        p = atomicAdd(&cur[d.w >> 8], 1); epart[p] = (unsigned int)s.w | ((unsigned int)(d.w & 255) << 17);
    }
    for (int i = lo + (nv << 2) + t; i < hi; i += 256) {
        int d = dst[i];
        int pos = atomicAdd(&cur[d >> 8], 1);
        epart[pos] = (unsigned int)src[i] | ((unsigned int)(d & 255) << 17);
    }
}

// P4: per-bucket fine sort with padded per-node lists (pad src = N).
// 256 nodes per bucket; full 256-thread scan. colidx stores BYTE offsets
// (src<<7) of hs rows so k_agg needs no per-lane address shift.
__global__ __launch_bounds__(256) void k_fine(const unsigned int* __restrict__ epart,
                                              const int* __restrict__ starts,
                                              int* __restrict__ deg,
                                              int* __restrict__ rowptr,
                                              float* __restrict__ dis,
                                              int* __restrict__ colidx, int N) {
    __shared__ unsigned int eb[FCAP];
    __shared__ int cnt[256], sc[256], cur[256];
    int j = blockIdx.x, t = threadIdx.x;
    int n0 = j << 8;
    int nn = min(256, N - n0);
    int s = starts[j], e = starts[j + 1];
    int m = e - s;
    int pbase = s + j * BPAD;
    cnt[t] = 0;
    __syncthreads();
    for (int i = t; i < m; i += 256) {
        unsigned int p = epart[s + i];
        if (i < FCAP) eb[i] = p;
        atomicAdd(&cnt[p >> 17], 1);
    }
    __syncthreads();
    int pcv = (cnt[t] + 7) & ~7;
    sc[t] = pcv;
    __syncthreads();
    for (int d = 1; d < 256; d <<= 1) {
        int u = (t >= d) ? sc[t - d] : 0;
        __syncthreads();
        sc[t] += u;
        __syncthreads();
    }
    if (t < nn) {
        int c = cnt[t];
        int rp = pbase + sc[t] - pcv;
        deg[n0 + t] = c;
        rowptr[n0 + t] = rp;
        dis[n0 + t] = rsqrtf((float)c + 1.0f);
        cur[t] = rp;
    }
    __syncthreads();
    for (int i = t; i < m; i += 256) {
        unsigned int p = (i < FCAP) ? eb[i] : epart[s + i];
        int pos = atomicAdd(&cur[p >> 17], 1);
        colidx[pos] = (int)((p & 0x1FFFF) << 7);   // byte offset of hs row
    }
    __syncthreads();
    if (t < nn) {
        int endp = rowptr[n0 + t] + ((cnt[t] + 7) & ~7);
        for (int q = cur[t]; q < endp; ++q) colidx[q] = N << 7;  // dummy row
    }
}

// MFMA GEMM: C[64x64] per block = A[64xK] * W[Kx64]; bf16 inputs, fp32 acc.
// Epilogue scales by dis[row], stores bf16 hs. ABF16: A already bf16.
template <int K, int ABF16>
__global__ __launch_bounds__(256) void k_gemm_mfma(const void* __restrict__ Ap,
                                                   const float* __restrict__ W,
                                                   const float* __restrict__ dis,
                                                   unsigned short* __restrict__ hs,
                                                   int N) {
    constexpr int AS = K + 8;
    __shared__ unsigned short As[64 * AS];
    __shared__ unsigned short Bt[64 * AS];
    const int tid = threadIdx.x;
    const int r0 = blockIdx.x * 64;

    for (int idx = tid; idx < K * 64; idx += 256) {
        int k = idx >> 6, n = idx & 63;
        Bt[n * AS + k] = f2bf(W[idx]);
    }
    if (ABF16) {
        const unsigned short* A = (const unsigned short*)Ap;
        for (int idx = tid; idx < 64 * (K / 8); idx += 256) {
            int row = idx / (K / 8), c8 = idx % (K / 8);
            int gr = r0 + row;
            uint4 v = (gr < N) ? *(const uint4*)&A[(size_t)gr * K + c8 * 8]
                               : make_uint4(0u, 0u, 0u, 0u);
            *(uint4*)&As[row * AS + c8 * 8] = v;
        }
    } else {
        const float* A = (const float*)Ap;
        for (int idx = tid; idx < 64 * (K / 4); idx += 256) {
            int row = idx / (K / 4), kq = idx % (K / 4);
            int gr = r0 + row;
            float4 a = (gr < N) ? ((const float4*)(A + (size_t)gr * K))[kq]
                                : make_float4(0.f, 0.f, 0.f, 0.f);
            ushort4 v;
            v.x = f2bf(a.x); v.y = f2bf(a.y); v.z = f2bf(a.z); v.w = f2bf(a.w);
            *(ushort4*)&As[row * AS + kq * 4] = v;
        }
    }
    __syncthreads();

    const int w = tid >> 6, lane = tid & 63;
    const int m = lane & 15, quad = lane >> 4;
    floatx4 acc0 = {0.f, 0.f, 0.f, 0.f};
    floatx4 acc1 = {0.f, 0.f, 0.f, 0.f};
    floatx4 acc2 = {0.f, 0.f, 0.f, 0.f};
    floatx4 acc3 = {0.f, 0.f, 0.f, 0.f};
#pragma unroll
    for (int s = 0; s < K / 32; ++s) {
        int ko = s * 32 + quad * 8;
        short8 a  = *(const short8*)&As[(w * 16 + m) * AS + ko];
        short8 b0 = *(const short8*)&Bt[(0 * 16 + m) * AS + ko];
        short8 b1 = *(const short8*)&Bt[(1 * 16 + m) * AS + ko];
        short8 b2 = *(const short8*)&Bt[(2 * 16 + m) * AS + ko];
        short8 b3 = *(const short8*)&Bt[(3 * 16 + m) * AS + ko];
        acc0 = __builtin_amdgcn_mfma_f32_16x16x32_bf16(a, b0, acc0, 0, 0, 0);
        acc1 = __builtin_amdgcn_mfma_f32_16x16x32_bf16(a, b1, acc1, 0, 0, 0);
        acc2 = __builtin_amdgcn_mfma_f32_16x16x32_bf16(a, b2, acc2, 0, 0, 0);
        acc3 = __builtin_amdgcn_mfma_f32_16x16x32_bf16(a, b3, acc3, 0, 0, 0);
    }
#pragma unroll
    for (int r = 0; r < 4; ++r) {
        int gr = r0 + w * 16 + quad * 4 + r;
        if (gr < N) {
            float dn = dis[gr];
            size_t base = (size_t)gr * 64 + m;
            hs[base + 0]  = f2bf(acc0[r] * dn);
            hs[base + 16] = f2bf(acc1[r] * dn);
            hs[base + 32] = f2bf(acc2[r] * dn);
            hs[base + 48] = f2bf(acc3[r] * dn);
        }
    }
}

// One wave per node. lane = eslot(0..7) x ch-octet(0..7). 16B uint4 gathers
// -> 8 edges per VMEM instruction. Padded x8 lists (dummy byte-off N<<7).
// v_pk_add_f32 packed accumulate; colidx holds pre-shifted byte offsets.
template <int RELU>
__global__ __launch_bounds__(256) void k_agg(const unsigned short* __restrict__ hs,
                                             const int* __restrict__ rowptr,
                                             const int* __restrict__ deg,
                                             const int* __restrict__ colidx,
                                             const float* __restrict__ dis,
                                             const float* __restrict__ bias,
                                             unsigned short* __restrict__ outp,
                                             int N) {
    int node = blockIdx.x * 4 + (threadIdx.x >> 6);
    if (node >= N) return;
    int lane = threadIdx.x & 63;
    int eslot = lane >> 3;   // 0..7
    int cq = lane & 7;       // channel octet

    int start = rowptr[node];
    int cnt = deg[node];
    int pcnt = (cnt + 7) & ~7;
    const int* ci = colidx + start + eslot;
    const char* hb = (const char*)hs + cq * 16;
    f32x2 acc[4];
    acc[0] = (f32x2){0.f, 0.f};
    acc[1] = (f32x2){0.f, 0.f};
    acc[2] = (f32x2){0.f, 0.f};
    acc[3] = (f32x2){0.f, 0.f};

    int i = 0;
    if (pcnt & 8) {
        int o0 = ci[0];
        uint4 a0 = *(const uint4*)(hb + o0);
        accp(acc, a0);
        i = 8;
    }
    if (pcnt & 16) {
        int o0 = ci[i], o1 = ci[i + 8];
        uint4 a0 = *(const uint4*)(hb + o0);
        uint4 a1 = *(const uint4*)(hb + o1);
        accp(acc, a0);
        accp(acc, a1);
        i += 16;
    }
    for (; i < pcnt; i += 32) {
        int o0 = ci[i + 0], o1 = ci[i + 8], o2 = ci[i + 16], o3 = ci[i + 24];
        uint4 a0 = *(const uint4*)(hb + o0);
        uint4 a1 = *(const uint4*)(hb + o1);
        uint4 a2 = *(const uint4*)(hb + o2);
        uint4 a3 = *(const uint4*)(hb + o3);
        accp(acc, a0);
        accp(acc, a1);
        accp(acc, a2);
        accp(acc, a3);
    }

#pragma unroll
    for (int q = 0; q < 4; ++q) {
        f32x2 t;
        t.x = __shfl_xor(acc[q].x, 8, 64);
        t.y = __shfl_xor(acc[q].y, 8, 64);
        asm("v_pk_add_f32 %0, %1, %0" : "+v"(acc[q]) : "v"(t));
        t.x = __shfl_xor(acc[q].x, 16, 64);
        t.y = __shfl_xor(acc[q].y, 16, 64);
        asm("v_pk_add_f32 %0, %1, %0" : "+v"(acc[q]) : "v"(t));
        t.x = __shfl_xor(acc[q].x, 32, 64);
        t.y = __shfl_xor(acc[q].y, 32, 64);
        asm("v_pk_add_f32 %0, %1, %0" : "+v"(acc[q]) : "v"(t));
    }

    if (eslot == 0) {
        uint4 sv = *(const uint4*)(hb + ((size_t)node << 7));
        accp(acc, sv);  // self-loop row (hs = dis*h), same accumulation order
        float dn = dis[node];
        float4 blo = *(const float4*)&bias[cq * 8];
        float4 bhi = *(const float4*)&bias[cq * 8 + 4];
        float bb[8] = {blo.x, blo.y, blo.z, blo.w, bhi.x, bhi.y, bhi.z, bhi.w};
        unsigned short o[8];
#pragma unroll
        for (int q = 0; q < 4; ++q) {
            float v0 = dn * acc[q].x + bb[2 * q + 0];
            float v1 = dn * acc[q].y + bb[2 * q + 1];
            if (RELU) {
                v0 = fmaxf(v0, 0.f);
                v1 = fmaxf(v1, 0.f);
            }
            o[2 * q + 0] = f2bf(v0);
            o[2 * q + 1] = f2bf(v1);
        }
        uint4 ov;
        ov.x = (unsigned int)o[0] | ((unsigned int)o[1] << 16);
        ov.y = (unsigned int)o[2] | ((unsigned int)o[3] << 16);
        ov.z = (unsigned int)o[4] | ((unsigned int)o[5] << 16);
        ov.w = (unsigned int)o[6] | ((unsigned int)o[7] << 16);
        *(uint4*)&outp[(size_t)node * 64 + cq * 8] = ov;
    }
}

// Fused mean-pool + FC head: one block (4 waves) per graph. Binary-search node
// range in sorted batch; 4 waves stripe the rows; LDS combine; 64x10 matvec.
__global__ __launch_bounds__(256) void k_head2(const unsigned short* __restrict__ h,
                                               const int* __restrict__ batch,
                                               const float* __restrict__ Wfc,
                                               const float* __restrict__ bfc,
                                               float* __restrict__ out, int N) {
    __shared__ float part[4][64];
    __shared__ float p[64];
    int g = blockIdx.x, t = threadIdx.x;
    int w = t >> 6, lane = t & 63;
    int lo = 0, hi = N;
    while (lo < hi) { int mid = (lo + hi) >> 1; if (batch[mid] < g) lo = mid + 1; else hi = mid; }
    int s = lo;
    hi = N;
    while (lo < hi) { int mid = (lo + hi) >> 1; if (batch[mid] < g + 1) lo = mid + 1; else hi = mid; }
    int e = lo;
    float acc = 0.f;
    int n = s + w;
    for (; n + 12 < e; n += 16) {
        float a0 = bf2f(h[(size_t)(n + 0) * 64 + lane]);
        float a1 = bf2f(h[(size_t)(n + 4) * 64 + lane]);
        float a2 = bf2f(h[(size_t)(n + 8) * 64 + lane]);
        float a3 = bf2f(h[(size_t)(n + 12) * 64 + lane]);
        acc += (a0 + a1) + (a2 + a3);
    }
    for (; n < e; n += 4) acc += bf2f(h[(size_t)n * 64 + lane]);
    part[w][lane] = acc;
    __syncthreads();
    if (w == 0) {
        float a = (part[0][lane] + part[1][lane]) + (part[2][lane] + part[3][lane]);
        float cntf = (float)max(e - s, 1);
        p[lane] = a / cntf;
    }
    __syncthreads();
    if (t < 10) {
        float o = bfc[t];
#pragma unroll
        for (int hh = 0; hh < 64; ++hh) o += p[hh] * Wfc[hh * 10 + t];
        out[g * 10 + t] = o;
    }
}

extern "C" void kernel_launch(void* const* d_in, const int* in_sizes, int n_in,
                              void* d_out, int out_size, void* d_ws, size_t ws_size,
                              hipStream_t stream) {
    const float* x = (const float*)d_in[0];
    const int* eidx = (const int*)d_in[1];
    const int* batch = (const int*)d_in[2];
    const float* W1 = (const float*)d_in[3];
    const float* b1 = (const float*)d_in[4];
    const float* W2 = (const float*)d_in[5];
    const float* b2 = (const float*)d_in[6];
    const float* W3 = (const float*)d_in[7];
    const float* b3 = (const float*)d_in[8];
    const float* Wfc = (const float*)d_in[9];
    const float* bfc = (const float*)d_in[10];
    float* out = (float*)d_out;

    const int N = in_sizes[0] / 128;  // 100000
    const int E = in_sizes[1] / 2;    // 3200000
    const int G = out_size / 10;      // 512
    const int NB = (N + 255) / 256;   // 391 buckets
    int chunk = ((E + NBLK - 1) / NBLK + 3) & ~3;  // 16B-aligned chunk starts

    char* ws = (char*)d_ws;
    size_t off = 0;
    auto alloc = [&](size_t bytes) -> char* {
        char* p = ws + off;
        off = (off + bytes + 511) & ~(size_t)511;
        return p;
    };
    int* deg = (int*)alloc((size_t)N * 4);
    int* rowptr = (int*)alloc((size_t)N * 4);
    float* dis = (float*)alloc((size_t)N * 4);
    int* starts = (int*)alloc((size_t)(MAXNB + 1) * 4);
    int* btotal = (int*)alloc((size_t)MAXNB * 4);
    int* blockhist = (int*)alloc((size_t)NB * NBLK * 4);
    unsigned int* epart = (unsigned int*)alloc((size_t)E * 4);
    int* colidx = (int*)alloc(((size_t)E + (size_t)NB * BPAD) * 4);
    unsigned short* hsA = (unsigned short*)alloc((size_t)(N + 1) * 64 * 2);
    unsigned short* hsB = (unsigned short*)alloc((size_t)(N + 1) * 64 * 2);
    unsigned short* obufb = (unsigned short*)alloc((size_t)N * 64 * 2);

    const int* esrc = eidx;
    const int* edst = eidx + E;

    k_hist<<<NBLK, 256, 0, stream>>>(edst, blockhist, E, chunk, NB);
    k_bscan<<<NB, 256, 0, stream>>>(blockhist, btotal);
    k_sscan<<<1, 256, 0, stream>>>(btotal, starts, NB, hsA, hsB, N);
    k_part<<<NBLK, 256, 0, stream>>>(esrc, edst, blockhist, starts, epart, E, chunk, NB);
    k_fine<<<NB, 256, 0, stream>>>(epart, starts, deg, rowptr, dis, colidx, N);

    int gblk = (N + 63) / 64;
    k_gemm_mfma<128, 0><<<gblk, 256, 0, stream>>>(x, W1, dis, hsA, N);
    k_agg<1><<<(N + 3) / 4, 256, 0, stream>>>(hsA, rowptr, deg, colidx, dis, b1, obufb, N);
    k_gemm_mfma<64, 1><<<gblk, 256, 0, stream>>>(obufb, W2, dis, hsB, N);
    k_agg<1><<<(N + 3) / 4, 256, 0, stream>>>(hsB, rowptr, deg, colidx, dis, b2, obufb, N);
    k_gemm_mfma<64, 1><<<gblk, 256, 0, stream>>>(obufb, W3, dis, hsA, N);
    k_agg<0><<<(N + 3) / 4, 256, 0, stream>>>(hsA, rowptr, deg, colidx, dis, b3, obufb, N);

    k_head2<<<G, 256, 0, stream>>>(obufb, batch, Wfc, bfc, out, N);
}